// Round 7
// baseline (2005.348 us; speedup 1.0000x reference)
//
#include <hip/hip_runtime.h>
#include <stdint.h>

// Problem constants
#define BB 64
#define LL 1024
#define DD 1024
#define CC 128
#define STOPTAG 127

// ---------------------------------------------------------------------------
// K1: emis[b*L + l][c] = sum_k x[.][k] * W[k][c] + bias[c]   (pure f32)
// 128x128 tile, BK=32, 256 threads, 8x8 micro-tile.
// Double-buffered LDS, T14 split: issue kc+1 global loads BEFORE compute of
// kc, publish regs->LDS after compute, ONE raw barrier per kc. Global loads
// stay in flight under the 2048-FMA compute phase (~4096 cy >> HBM latency).
// ---------------------------------------------------------------------------
__global__ __launch_bounds__(256) void k_emis(const float* __restrict__ x,
                                              const float* __restrict__ W,
                                              const float* __restrict__ bias,
                                              float* __restrict__ emis) {
    __shared__ float a_t[2][32][132];   // [buf][k][row], 132 stride: 16B-aligned rows
    const int tid = threadIdx.x;
    const int bm  = blockIdx.x;
    const float* A = x + (size_t)bm * 128 * DD;
    const int tx = tid & 15, ty = tid >> 4;
    const int r0 = ty * 8, c0 = tx * 8;

    float acc[8][8];
#pragma unroll
    for (int i = 0; i < 8; ++i)
#pragma unroll
        for (int j = 0; j < 8; ++j) acc[i][j] = 0.0f;

    float4 rs[4];
    // prologue: stage kc=0 through regs into buf 0
#pragma unroll
    for (int i = 0; i < 4; ++i) {
        int s = tid + 256 * i, row = s >> 3, k0 = (s & 7) * 4;
        rs[i] = *(const float4*)(A + (size_t)row * DD + k0);
    }
#pragma unroll
    for (int i = 0; i < 4; ++i) {
        int s = tid + 256 * i, row = s >> 3, k0 = (s & 7) * 4;
        a_t[0][k0 + 0][row] = rs[i].x;
        a_t[0][k0 + 1][row] = rs[i].y;
        a_t[0][k0 + 2][row] = rs[i].z;
        a_t[0][k0 + 3][row] = rs[i].w;
    }
    __syncthreads();

    for (int kc = 0; kc < 32; ++kc) {
        if (kc + 1 < 32) {     // issue next-tile loads; in flight across compute
#pragma unroll
            for (int i = 0; i < 4; ++i) {
                int s = tid + 256 * i, row = s >> 3, k0 = (s & 7) * 4;
                rs[i] = *(const float4*)(A + (size_t)row * DD + (kc + 1) * 32 + k0);
            }
        }
        const float* Wp = W + (size_t)kc * 32 * CC;
        const float (*at)[132] = a_t[kc & 1];
#pragma unroll
        for (int k = 0; k < 32; ++k) {
            float4 w0 = *(const float4*)(Wp + k * CC + c0);
            float4 w1 = *(const float4*)(Wp + k * CC + c0 + 4);
            float4 pa = *(const float4*)&at[k][r0];
            float4 pb = *(const float4*)&at[k][r0 + 4];
            float av[8] = {pa.x, pa.y, pa.z, pa.w, pb.x, pb.y, pb.z, pb.w};
            float wv[8] = {w0.x, w0.y, w0.z, w0.w, w1.x, w1.y, w1.z, w1.w};
#pragma unroll
            for (int i = 0; i < 8; ++i)
#pragma unroll
                for (int j = 0; j < 8; ++j)
                    acc[i][j] = fmaf(av[i], wv[j], acc[i][j]);
        }
        if (kc + 1 < 32) {     // publish staged tile, single barrier per kc
#pragma unroll
            for (int i = 0; i < 4; ++i) {
                int s = tid + 256 * i, row = s >> 3, k0 = (s & 7) * 4;
                a_t[(kc + 1) & 1][k0 + 0][row] = rs[i].x;
                a_t[(kc + 1) & 1][k0 + 1][row] = rs[i].y;
                a_t[(kc + 1) & 1][k0 + 2][row] = rs[i].z;
                a_t[(kc + 1) & 1][k0 + 3][row] = rs[i].w;
            }
            asm volatile("s_waitcnt lgkmcnt(0)" ::: "memory");
            __builtin_amdgcn_s_barrier();
        }
    }
    float4 bv0 = *(const float4*)(bias + c0);
    float4 bv1 = *(const float4*)(bias + c0 + 4);
    float bb[8] = {bv0.x, bv0.y, bv0.z, bv0.w, bv1.x, bv1.y, bv1.z, bv1.w};
#pragma unroll
    for (int i = 0; i < 8; ++i) {
        size_t row = (size_t)bm * 128 + r0 + i;
        float4 o0 = make_float4(acc[i][0] + bb[0], acc[i][1] + bb[1],
                                acc[i][2] + bb[2], acc[i][3] + bb[3]);
        float4 o1 = make_float4(acc[i][4] + bb[4], acc[i][5] + bb[5],
                                acc[i][6] + bb[6], acc[i][7] + bb[7]);
        *(float4*)(emis + row * CC + c0)     = o0;
        *(float4*)(emis + row * CC + c0 + 4) = o1;
    }
}

// ---------------------------------------------------------------------------
// Mask may arrive as 1-byte bool or widened int32. Discriminator: byte [1]
// (len >= 512 so bool-bytes give mask[1]==1; int32 gives 0).
// ---------------------------------------------------------------------------

// K2: Viterbi forward (round-5 structure — best measured, 447us, 0 conflicts).
// 8 waves per batch, wave w owns 16-wide cp window. One raw s_barrier +
// lgkmcnt-only wait per step; global loads/stores never vmcnt-drained.
__global__ __launch_bounds__(512) void k_forward(float* __restrict__ emis,
                                                 const unsigned char* __restrict__ mask,
                                                 const float* __restrict__ T) {
    const int b    = blockIdx.x;
    const int tid  = threadIdx.x;
    const int w    = tid >> 6;
    const int lane = tid & 63;

    __shared__ float part[2][8][CC];
    __shared__ int s_len;
    if (tid == 0) s_len = 0;
    __syncthreads();

    // sequence length (prefix mask -> popcount); 256 threads cover 1024 elems
    if (tid < 256) {
        const bool is_b8 = (mask[1] != 0);
        int c;
        if (is_b8) {
            const uchar4* m4 = (const uchar4*)(mask + (size_t)b * LL);
            uchar4 mv = m4[tid];
            c = (mv.x != 0) + (mv.y != 0) + (mv.z != 0) + (mv.w != 0);
        } else {
            const int4* m4 = (const int4*)((const int*)(const void*)mask + (size_t)b * LL);
            int4 mv = m4[tid];
            c = (mv.x != 0) + (mv.y != 0) + (mv.z != 0) + (mv.w != 0);
        }
        atomicAdd(&s_len, c);
    }
    __syncthreads();
    const int len = s_len;

    float t0[16], t1[16];
#pragma unroll
    for (int j = 0; j < 16; ++j) {
        t0[j] = T[(size_t)(w * 16 + j) * CC + lane];
        t1[j] = T[(size_t)(w * 16 + j) * CC + lane + 64];
    }

    const int cc_fin = w * 16 + (lane & 15);
    float* eb = emis + (size_t)b * LL * CC;   // emis rows become score rows in place

    float s_val = 0.0f;
    float e_cur = eb[cc_fin];
    float e_n1  = eb[CC + cc_fin];

    for (int l = 0; l < len; ++l) {
        int lp = l + 2 < len ? l + 2 : len - 1;
        float e_n2 = eb[(size_t)lp * CC + cc_fin];

        float acc0 = -INFINITY, acc1 = -INFINITY;
#pragma unroll
        for (int jj = 0; jj < 8; ++jj) {
            float sa = __int_as_float(__builtin_amdgcn_readlane(__float_as_int(s_val), 2 * jj));
            float sb = __int_as_float(__builtin_amdgcn_readlane(__float_as_int(s_val), 2 * jj + 1));
            acc0 = fmaxf(fmaxf(sa + t0[2 * jj], sb + t0[2 * jj + 1]), acc0);
            acc1 = fmaxf(fmaxf(sa + t1[2 * jj], sb + t1[2 * jj + 1]), acc1);
        }
        int p = l & 1;
        part[p][w][lane]      = acc0;
        part[p][w][lane + 64] = acc1;
        asm volatile("s_waitcnt lgkmcnt(0)" ::: "memory");
        __builtin_amdgcn_s_barrier();
        float m0 = fmaxf(part[p][0][cc_fin], part[p][1][cc_fin]);
        float m1 = fmaxf(part[p][2][cc_fin], part[p][3][cc_fin]);
        float m2 = fmaxf(part[p][4][cc_fin], part[p][5][cc_fin]);
        float m3 = fmaxf(part[p][6][cc_fin], part[p][7][cc_fin]);
        float mx = fmaxf(fmaxf(m0, m1), fmaxf(m2, m3));
        s_val = mx + e_cur;
        eb[(size_t)l * CC + cc_fin] = s_val;   // 4-way duplicate store, same value
        e_cur = e_n1;
        e_n1  = e_n2;
    }
}

// ---------------------------------------------------------------------------
// K3: backtrack. One wave per batch. Exact first-index argmax per step.
// Score rows are HBM-resident (32MB > L2): 6-row register prefetch window
// (issued ~6 dependent asteps (~1800cy) before use) hides miss latency.
// ---------------------------------------------------------------------------
__device__ __forceinline__ unsigned mono_u32(float f) {
    unsigned u = __float_as_uint(f);
    return u ^ (unsigned)(((int)u >> 31) | 0x80000000);
}

__device__ __forceinline__ unsigned dpp_max64(unsigned m) {
    unsigned t;
    t = (unsigned)__builtin_amdgcn_update_dpp(0, (int)m, 0x111, 0xF, 0xF, true); m = m > t ? m : t;
    t = (unsigned)__builtin_amdgcn_update_dpp(0, (int)m, 0x112, 0xF, 0xF, true); m = m > t ? m : t;
    t = (unsigned)__builtin_amdgcn_update_dpp(0, (int)m, 0x114, 0xF, 0xF, true); m = m > t ? m : t;
    t = (unsigned)__builtin_amdgcn_update_dpp(0, (int)m, 0x118, 0xF, 0xF, true); m = m > t ? m : t;
    t = (unsigned)__builtin_amdgcn_update_dpp(0, (int)m, 0x142, 0xF, 0xF, true); m = m > t ? m : t;
    t = (unsigned)__builtin_amdgcn_update_dpp(0, (int)m, 0x143, 0xF, 0xF, true); m = m > t ? m : t;
    return m;   // lane 63 holds the wave max
}

__device__ __forceinline__ int astep(float sA, float sB, int row,
                                     const float* ldsT, int lane) {
    int q = (row & 7) << 2;
    float c0 = sA + ldsT[row * CC + (lane ^ q)];
    float c1 = sB + ldsT[row * CC + ((lane ^ q) + 64)];
    unsigned m0 = mono_u32(c0), m1 = mono_u32(c1);
    unsigned m = m0 > m1 ? m0 : m1;
    m = dpp_max64(m);
    unsigned mx = (unsigned)__builtin_amdgcn_readlane((int)m, 63);
    unsigned long long bl0 = __ballot(m0 == mx);
    unsigned long long bl1 = __ballot(m1 == mx);
    return bl0 ? __builtin_ctzll(bl0) : (64 + __builtin_ctzll(bl1));
}

__global__ __launch_bounds__(64) void k_back(const float* __restrict__ slog,
                                             const unsigned char* __restrict__ mask,
                                             const float* __restrict__ T,
                                             int* __restrict__ out) {
    const int b    = blockIdx.x;
    const int lane = threadIdx.x;
    __shared__ float ldsT[CC * CC];   // T transposed, XOR-swizzled

    // 1) sequence length via ballots (fast; needed for prefetch addresses)
    int len = 0;
    {
        const bool is_b8 = (mask[1] != 0);
        if (is_b8) {
            const unsigned char* mrow = mask + (size_t)b * LL;
            for (int i = 0; i < 16; ++i)
                len += (int)__popcll(__ballot(mrow[lane + i * 64] != 0));
        } else {
            const int* mrow = (const int*)(const void*)mask + (size_t)b * LL;
            for (int i = 0; i < 16; ++i)
                len += (int)__popcll(__ballot(mrow[lane + i * 64] != 0));
        }
    }

    const float* sb = slog + (size_t)b * LL * CC;
    int* ob         = out + (size_t)b * LL;

    // 2) issue score-row prefetches (rows len-1 .. len-7); ldsT staging below
    //    gives them ~256 global loads of cover before first use. len>=512.
    float f0 = sb[(size_t)(len - 1) * CC + lane];
    float f1 = sb[(size_t)(len - 1) * CC + lane + 64];
    float A0 = sb[(size_t)(len - 2) * CC + lane];
    float A1 = sb[(size_t)(len - 2) * CC + lane + 64];
    float B0 = sb[(size_t)(len - 3) * CC + lane];
    float B1 = sb[(size_t)(len - 3) * CC + lane + 64];
    float C0 = sb[(size_t)(len - 4) * CC + lane];
    float C1 = sb[(size_t)(len - 4) * CC + lane + 64];
    float D0 = sb[(size_t)(len - 5) * CC + lane];
    float D1 = sb[(size_t)(len - 5) * CC + lane + 64];
    float E0 = sb[(size_t)(len - 6) * CC + lane];
    float E1 = sb[(size_t)(len - 6) * CC + lane + 64];
    float F0 = sb[(size_t)(len - 7) * CC + lane];
    float F1 = sb[(size_t)(len - 7) * CC + lane + 64];

    // 3) stage T transposed into LDS (coalesced reads, swizzled writes)
    {
        int q = (lane & 7) << 2;
        for (int r = 0; r < CC; ++r) {
            float v0 = T[(size_t)r * CC + lane];
            float v1 = T[(size_t)r * CC + lane + 64];
            ldsT[lane * CC + (r ^ q)]        = v0;
            ldsT[(lane + 64) * CC + (r ^ q)] = v1;
        }
    }
    __syncthreads();

    // zero-fill beyond the sequence
    for (int l = len + lane; l < LL; l += 64) ob[l] = 0;

    // last tag: argmax_c( s_final[c] + T[c][STOP] )
    int cur = astep(f0, f1, STOPTAG, ldsT, lane);
    if (lane == 0) ob[len - 1] = cur;

    // walk r = len-2 .. 0 with a 6-row register window, 2 rows/iter
    int r = len - 2;
    while (r >= 2) {
        cur = astep(A0, A1, cur, ldsT, lane);
        if (lane == 0) ob[r] = cur;
        cur = astep(B0, B1, cur, ldsT, lane);
        if (lane == 0) ob[r - 1] = cur;
        A0 = C0; A1 = C1; B0 = D0; B1 = D1;
        C0 = E0; C1 = E1; D0 = F0; D1 = F1;
        int g0 = r - 6 >= 0 ? r - 6 : 0;
        int g1 = r - 7 >= 0 ? r - 7 : 0;
        E0 = sb[(size_t)g0 * CC + lane];
        E1 = sb[(size_t)g0 * CC + lane + 64];
        F0 = sb[(size_t)g1 * CC + lane];
        F1 = sb[(size_t)g1 * CC + lane + 64];
        r -= 2;
    }
    if (r == 1) {
        cur = astep(A0, A1, cur, ldsT, lane);
        if (lane == 0) ob[1] = cur;
        cur = astep(B0, B1, cur, ldsT, lane);
        if (lane == 0) ob[0] = cur;
    } else if (r == 0) {
        cur = astep(A0, A1, cur, ldsT, lane);
        if (lane == 0) ob[0] = cur;
    }
}

// ---------------------------------------------------------------------------
extern "C" void kernel_launch(void* const* d_in, const int* in_sizes, int n_in,
                              void* d_out, int out_size, void* d_ws, size_t ws_size,
                              hipStream_t stream) {
    (void)in_sizes; (void)n_in; (void)out_size; (void)ws_size;
    const float* x    = (const float*)d_in[0];
    const unsigned char* mask = (const unsigned char*)d_in[1];
    // d_in[2] = y (unused by the reference output)
    const float* W    = (const float*)d_in[3];
    const float* bias = (const float*)d_in[4];
    const float* T    = (const float*)d_in[5];
    int* out = (int*)d_out;

    float* emis = (float*)d_ws;   // 32 MB; score rows overwrite emis in place

    k_emis<<<dim3(512), dim3(256), 0, stream>>>(x, W, bias, emis);
    k_forward<<<dim3(BB), dim3(512), 0, stream>>>(emis, mask, T);
    k_back<<<dim3(BB), dim3(64), 0, stream>>>(emis, mask, T, out);
}